// Round 3
// baseline (19184.105 us; speedup 1.0000x reference)
//
#include <hip/hip_runtime.h>
#include <hip/hip_bf16.h>
#include <hip/hip_cooperative_groups.h>

namespace cg = cooperative_groups;

typedef __bf16 bf16x8 __attribute__((ext_vector_type(8)));
typedef __bf16 bf16x4 __attribute__((ext_vector_type(4)));
typedef float  f32x4  __attribute__((ext_vector_type(4)));

#define NB   64      // batch
#define NT   512     // timesteps
#define ND   1024    // input dim
#define NU   1024    // units
#define NG4  4096    // 4*U

__device__ __forceinline__ f32x4 mfma16(bf16x8 a, bf16x8 b, f32x4 c) {
  return __builtin_amdgcn_mfma_f32_16x16x32_bf16(a, b, c, 0, 0, 0);
}

// ---------- transpose + convert: in[R][C] f32 -> out[C][R] bf16 ----------
__global__ void tcvt_kernel(const float* __restrict__ in, __bf16* __restrict__ out,
                            int R, int C) {
  __shared__ float tile[32][33];
  int c0 = blockIdx.x * 32, r0 = blockIdx.y * 32;
  int tx = threadIdx.x, ty = threadIdx.y;
#pragma unroll
  for (int i = 0; i < 32; i += 8)
    tile[ty + i][tx] = in[(size_t)(r0 + ty + i) * C + (c0 + tx)];
  __syncthreads();
#pragma unroll
  for (int i = 0; i < 32; i += 8)
    out[(size_t)(c0 + ty + i) * R + (r0 + tx)] = (__bf16)tile[tx][ty + i];
}

// ---------- phase 1: xp[t][b][col] = x[b][t][:] @ Wx + bias ----------
// A rows are remapped: rho = t*64 + b, so xp comes out [T][B][4U] (bf16).
// wxT is Wx transposed: [4096][1024] bf16.
#define LDK 72   // 64 + 8 pad elements; 144B row stride (16B aligned, 2-way banks)
__global__ __launch_bounds__(256, 2)
void xproj_kernel(const float* __restrict__ x, const __bf16* __restrict__ wxT,
                  const float* __restrict__ bias, __bf16* __restrict__ xp) {
  __shared__ __bf16 a_lds[128 * LDK];
  __shared__ __bf16 b_lds[128 * LDK];
  const int tid = threadIdx.x;
  const int rr = tid >> 1, q = tid & 1;           // staging: 128 rows x 2 k-halves
  const int rho0 = blockIdx.x * 128;
  const int col0 = blockIdx.y * 128;

  const int rho = rho0 + rr;
  const int bb = rho & 63, tt = rho >> 6;
  const float*  asrc = x   + ((size_t)bb * NT + tt) * ND + q * 32;
  const __bf16* bsrc = wxT + (size_t)(col0 + rr) * ND   + q * 32;

  const int l  = tid & 63, wv = tid >> 6;
  const int wm = wv >> 1,  wn = wv & 1;
  const int lr = l & 15,   lk = (l >> 4) * 8;

  f32x4 acc[4][4];
#pragma unroll
  for (int i = 0; i < 4; ++i)
#pragma unroll
    for (int j = 0; j < 4; ++j) { acc[i][j][0]=0.f; acc[i][j][1]=0.f; acc[i][j][2]=0.f; acc[i][j][3]=0.f; }

  for (int k0 = 0; k0 < ND; k0 += 64) {
    // stage A (fp32 -> bf16)
#pragma unroll
    for (int j = 0; j < 8; ++j) {
      f32x4 v = *reinterpret_cast<const f32x4*>(asrc + k0 + 4 * j);
      bf16x4 w; w[0]=(__bf16)v[0]; w[1]=(__bf16)v[1]; w[2]=(__bf16)v[2]; w[3]=(__bf16)v[3];
      *reinterpret_cast<bf16x4*>(&a_lds[rr * LDK + q * 32 + 4 * j]) = w;
    }
    // stage B (already bf16)
#pragma unroll
    for (int j = 0; j < 4; ++j) {
      bf16x8 v = *reinterpret_cast<const bf16x8*>(bsrc + k0 + 8 * j);
      *reinterpret_cast<bf16x8*>(&b_lds[rr * LDK + q * 32 + 8 * j]) = v;
    }
    __syncthreads();
#pragma unroll
    for (int kk = 0; kk < 2; ++kk) {
      bf16x8 av[4], bv[4];
#pragma unroll
      for (int i = 0; i < 4; ++i)
        av[i] = *reinterpret_cast<const bf16x8*>(&a_lds[(wm*64 + i*16 + lr) * LDK + kk*32 + lk]);
#pragma unroll
      for (int j = 0; j < 4; ++j)
        bv[j] = *reinterpret_cast<const bf16x8*>(&b_lds[(wn*64 + j*16 + lr) * LDK + kk*32 + lk]);
#pragma unroll
      for (int i = 0; i < 4; ++i)
#pragma unroll
        for (int j = 0; j < 4; ++j)
          acc[i][j] = mfma16(av[i], bv[j], acc[i][j]);
    }
    __syncthreads();
  }
  // epilogue: add bias, cvt, store (C/D layout: col=lane&15, row=(lane>>4)*4+r)
#pragma unroll
  for (int i = 0; i < 4; ++i)
#pragma unroll
    for (int j = 0; j < 4; ++j) {
      int col = col0 + wn*64 + j*16 + lr;
      float bv = bias[col];
#pragma unroll
      for (int r = 0; r < 4; ++r) {
        int row = rho0 + wm*64 + i*16 + (l >> 4) * 4 + r;
        xp[(size_t)row * NG4 + col] = (__bf16)(acc[i][j][r] + bv);
      }
    }
}

// ---------- phase 2: persistent cooperative scan over T ----------
// 256 wgs x 256 thr. wg owns 4 u-columns (16 z-cols with gates). Wh slice in LDS.
// h double-buffered bf16 in ws. One grid.sync per step.
#define WHS_LD 1032   // 1024 + 8 pad elements; 2064B stride
__global__ __launch_bounds__(256, 1)
void scan_kernel(const __bf16* __restrict__ xp, const __bf16* __restrict__ whT,
                 __bf16* __restrict__ hbuf, float* __restrict__ out) {
  __shared__ __bf16 whs[16 * WHS_LD];
  const int tid = threadIdx.x;
  const int wv = tid >> 6, l = tid & 63;
  const int lr = l & 15, lc = l >> 4;
  const int wg = blockIdx.x;
  // XCD-grouped u-slice: consecutive slices stay on one XCD for xp line reuse
  const int slice = ((wg & 7) << 5) | (wg >> 3);
  const int u0 = slice * 4;

  // load Wh slice: whs[c][k] = Wh[k][gate(c)*1024 + u0 + (c&3)] from whT rows
  {
    const int c = tid >> 4, seg = tid & 15;
    const int colg = ((c >> 2) << 10) + u0 + (c & 3);
    const __bf16* src = whT + (size_t)colg * NU + seg * 64;
#pragma unroll
    for (int m = 0; m < 8; ++m)
      *reinterpret_cast<bf16x8*>(&whs[c * WHS_LD + seg * 64 + 8 * m]) =
          *reinterpret_cast<const bf16x8*>(src + 8 * m);
  }
  __syncthreads();

  cg::grid_group grid = cg::this_grid();

  const int colg_l  = ((lr >> 2) << 10) + u0 + (lr & 3);  // this lane's z column
  const int rowbase = wv * 16 + lc * 4;                    // first of my 4 batch rows
  const int du = l & 3, sb = l & 48;
  float cst[4] = {0.f, 0.f, 0.f, 0.f};

  for (int t = 0; t < NT; ++t) {
    f32x4 acc;  acc[0]=0.f;  acc[1]=0.f;  acc[2]=0.f;  acc[3]=0.f;
    f32x4 acc2; acc2[0]=0.f; acc2[1]=0.f; acc2[2]=0.f; acc2[3]=0.f;
    if (t > 0) {
      const __bf16* hp = hbuf + ((t - 1) & 1) * (NB * NU) + (size_t)(wv * 16 + lr) * NU + lc * 8;
      const __bf16* bp = &whs[lr * WHS_LD + lc * 8];
#pragma unroll
      for (int it = 0; it < 32; it += 2) {
        bf16x8 a0 = *reinterpret_cast<const bf16x8*>(hp + it * 32);
        bf16x8 b0 = *reinterpret_cast<const bf16x8*>(bp + it * 32);
        bf16x8 a1 = *reinterpret_cast<const bf16x8*>(hp + it * 32 + 32);
        bf16x8 b1 = *reinterpret_cast<const bf16x8*>(bp + it * 32 + 32);
        acc  = mfma16(a0, b0, acc);
        acc2 = mfma16(a1, b1, acc2);
      }
      acc[0]+=acc2[0]; acc[1]+=acc2[1]; acc[2]+=acc2[2]; acc[3]+=acc2[3];
    }
    // z = x_proj + h@Wh   (bias folded into xp)
    const __bf16* xpt = xp + ((size_t)t * NB + rowbase) * NG4 + colg_l;
    float z[4];
#pragma unroll
    for (int r = 0; r < 4; ++r) z[r] = acc[r] + (float)xpt[(size_t)r * NG4];
    // gates: lane needs cols {du, 4+du, 8+du, 12+du} of its 16-lane group
#pragma unroll
    for (int r = 0; r < 4; ++r) {
      float zi = __shfl(z[r], sb + du,      64);
      float zf = __shfl(z[r], sb + 4 + du,  64);
      float zg = __shfl(z[r], sb + 8 + du,  64);
      float zo = __shfl(z[r], sb + 12 + du, 64);
      float ig = 1.f / (1.f + __expf(-zi));
      float fg = 1.f / (1.f + __expf(-zf));
      float gg = tanhf(zg);
      float og = 1.f / (1.f + __expf(-zo));
      cst[r] = fg * cst[r] + ig * gg;
      float hn = og * tanhf(cst[r]);
      if (lr < 4) {  // one writer per (b,u): gate-0 lanes (du == lr)
        int b = rowbase + r;
        int u = u0 + du;
        out[(size_t)b * ((size_t)NT * NU) + (size_t)t * NU + u] = hn;
        hbuf[(t & 1) * (NB * NU) + b * NU + u] = (__bf16)hn;
      }
    }
    if (t < NT - 1) grid.sync();
  }
}

// ---------- launch ----------
// ws layout (bytes):
//   [0,   8M)   wxT bf16 [4096][1024]
//   [8M, 16M)   whT bf16 [4096][1024]
//   [16M, 272M) xp  bf16 [512][64][4096]
//   [272M, ...) hbuf bf16 [2][64][1024]   (~286MB total needed)
extern "C" void kernel_launch(void* const* d_in, const int* in_sizes, int n_in,
                              void* d_out, int out_size, void* d_ws, size_t ws_size,
                              hipStream_t stream) {
  const float* x  = (const float*)d_in[0];
  const float* Wx = (const float*)d_in[1];
  const float* Wh = (const float*)d_in[2];
  const float* bias = (const float*)d_in[3];
  float* out = (float*)d_out;
  char* ws = (char*)d_ws;

  __bf16* wxT  = (__bf16*)(ws);
  __bf16* whT  = (__bf16*)(ws + (size_t)8 * 1024 * 1024);
  __bf16* xp   = (__bf16*)(ws + (size_t)16 * 1024 * 1024);
  __bf16* hbuf = (__bf16*)(ws + (size_t)16 * 1024 * 1024 + (size_t)NT * NB * NG4 * 2);

  dim3 tb(32, 8);
  tcvt_kernel<<<dim3(NG4 / 32, ND / 32), tb, 0, stream>>>(Wx, wxT, ND, NG4);
  tcvt_kernel<<<dim3(NG4 / 32, NU / 32), tb, 0, stream>>>(Wh, whT, NU, NG4);

  xproj_kernel<<<dim3(256, 32), 256, 0, stream>>>(x, wxT, bias, xp);

  const __bf16* xp_c  = xp;
  const __bf16* whT_c = whT;
  __bf16* hbuf_p = hbuf;
  float*  out_p  = out;
  void* args[] = {(void*)&xp_c, (void*)&whT_c, (void*)&hbuf_p, (void*)&out_p};
  hipLaunchCooperativeKernel((void*)scan_kernel, dim3(256), dim3(256), args, 0, stream);
}